// Round 12
// baseline (113.283 us; speedup 1.0000x reference)
//
#include <hip/hip_runtime.h>

#define NATOMS 8192
#define DD 128     // embedding dim
#define HH 256     // hidden dim
#define TI 4       // atoms per block in aggregation -- FROZEN (TI=8 fails: R7/R11)
#define MAXE 128   // max edges per atom (mean ~20, Poisson; 128 is >>6 sigma)
#define BM 32      // nodes per block in MFMA MLP
#define JT 2048    // j-tile staged in LDS (4 tiles of 24 KB)
#define KJ2KCAL 0.2390057361376673f

typedef __attribute__((ext_vector_type(8))) short bf16x8;  // 4 VGPRs
typedef __attribute__((ext_vector_type(4))) float f32x4;

// fp32 -> bf16 round-to-nearest-even (finite inputs)
__device__ inline unsigned short f2bf(float x) {
  unsigned int b = __builtin_bit_cast(unsigned int, x);
  b += 0x7FFFu + ((b >> 16) & 1u);
  return (unsigned short)(b >> 16);
}

// k_agg [R10-passing structure; only change: sweep reads positions from an
// LDS-staged copy of the SAME raw pos dwords]:
//  - blocks 0..63 also transpose W1 -> bf16 W1bfT; block 0 zeroes out.
//  - positions staged per 2048-atom tile with fully-coalesced linear dword
//    reads (the old sweep's per-lane stride-12 loads touched ~12 cache lines
//    per wave-load -- the diagnosed ~30us cost). ds_read at dword-stride 3:
//    64 lanes -> 2 lanes/bank = conflict-free.
//  - VALUES bit-identical: same bytes, same "10.0f * p" expression, same mask,
//    ballot order unchanged. Expand/phase-2 verbatim R10. TI=4 frozen.
__global__ __launch_bounds__(256) void k_agg(const float* __restrict__ pos,
                                             const int* __restrict__ types,
                                             const float* __restrict__ W1,
                                             const float* __restrict__ emb,
                                             unsigned short* __restrict__ W1bfT,
                                             unsigned short* __restrict__ aggbf,
                                             float* __restrict__ out) {
  __shared__ float spos[3 * JT];                         // 24 KB raw pos dwords
  __shared__ unsigned long long smask[TI][NATOMS / 64];  // 4 KB
  __shared__ float sw[TI][MAXE];
  __shared__ int   srow[TI][MAXE];
  __shared__ int   scnt[TI];
  const int tid = threadIdx.x;
  const int i0 = blockIdx.x * TI;

  // merged one-time prep (identical values to verified k_prep)
  if (blockIdx.x < 64) {
    int t = blockIdx.x * 256 + tid;         // 0..16383
    if (t == 0) out[0] = 0.0f;
    int n = t & 255;
    int kb = (t >> 8) * 4;                  // 0,4,..,252
#pragma unroll
    for (int i = 0; i < 4; ++i)
      W1bfT[n * HH + kb + i] = f2bf(W1[(kb + i) * HH + n]);  // read coalesced in n
  }

  float pix[TI], piy[TI], piz[TI];
#pragma unroll
  for (int m = 0; m < TI; ++m) {   // uniform addresses -> scalar loads
    pix[m] = 10.0f * pos[(i0 + m) * 3 + 0];
    piy[m] = 10.0f * pos[(i0 + m) * 3 + 1];
    piz[m] = 10.0f * pos[(i0 + m) * 3 + 2];
  }

  // sweep over 4 j-tiles; lanes cover 64 consecutive j -> ballot bit r <-> j
  for (int t = 0; t < NATOMS / JT; ++t) {
    __syncthreads();               // protect spos from previous tile's readers
    for (int idx = tid; idx < 3 * JT; idx += 256)
      spos[idx] = pos[3 * JT * t + idx];    // coalesced linear dwords
    __syncthreads();
#pragma unroll 4
    for (int jj = tid; jj < JT; jj += 256) {
      float pjx = 10.0f * spos[3 * jj + 0];
      float pjy = 10.0f * spos[3 * jj + 1];
      float pjz = 10.0f * spos[3 * jj + 2];
      int c = (JT * t + jj) >> 6;  // wave-uniform chunk id
#pragma unroll
      for (int m = 0; m < TI; ++m) {
        float dx = pix[m] - pjx, dy = piy[m] - pjy, dz = piz[m] - pjz;
        float d2 = dx * dx;
        d2 = fmaf(dy, dy, d2);
        d2 = fmaf(dz, dz, d2);
        // ref mask: d2 > 1e-12 && sqrt(d2) <= 5  <=>  1e-12 < d2 <= 25
        unsigned long long bal = __ballot(d2 > 1e-12f && d2 <= 25.0f);
        if ((tid & 63) == 0) smask[m][c] = bal;
      }
    }
  }
  __syncthreads();

  // scan + expand [verbatim R10]: wave m handles atom m; lane l owns chunks
  // {2l, 2l+1}; recompute d2/w with textually identical expressions.
  {
    const int m = tid >> 6;        // 0..3 (4 waves)
    const int l = tid & 63;
    unsigned long long mA = smask[m][2 * l];
    unsigned long long mB = smask[m][2 * l + 1];
    int cA = __popcll(mA), cB = __popcll(mB);
    int s = cA + cB;
    int scan = s;                  // inclusive prefix over 64 lanes
#pragma unroll
    for (int off = 1; off < 64; off <<= 1) {
      int t = __shfl_up(scan, off);
      if (l >= off) scan += t;
    }
    int excl = scan - s;
    if (l == 63) scnt[m] = scan;   // per-atom total
    float px = 10.0f * pos[(i0 + m) * 3 + 0];
    float py = 10.0f * pos[(i0 + m) * 3 + 1];
    float pz = 10.0f * pos[(i0 + m) * 3 + 2];
#pragma unroll
    for (int h = 0; h < 2; ++h) {
      unsigned long long mask = h ? mB : mA;
      int base = h ? excl + cA : excl;
      int cbase = 64 * (2 * l + h);
      while (mask) {
        int r = __ffsll((long long)mask) - 1;
        mask &= mask - 1;
        int j = cbase + r;
        if (base < MAXE) {
          float pjx = 10.0f * pos[j * 3 + 0];
          float pjy = 10.0f * pos[j * 3 + 1];
          float pjz = 10.0f * pos[j * 3 + 2];
          float dx = px - pjx, dy = py - pjy, dz = pz - pjz;
          float d2 = dx * dx;
          d2 = fmaf(dy, dy, d2);
          d2 = fmaf(dz, dz, d2);
          float w = __expf(-sqrtf(d2));
          sw[m][base] = w;
          srow[m][base] = types[j] * DD;
        }
        ++base;
      }
    }
  }
  __syncthreads();

  // phase 2 [verbatim R10]: 2 groups of 128 dims; group g -> atoms {g, g+2}
  const int d = tid & (DD - 1);
  const int g = tid >> 7;
#pragma unroll
  for (int mm = 0; mm < TI; mm += 2) {
    int m = g + mm;
    int nc = min(scnt[m], MAXE);
    float a = 0.0f;
#pragma unroll 4
    for (int e = 0; e < nc; ++e)
      a = fmaf(sw[m][e], emb[srow[m][e] + d], a);
    aggbf[(size_t)(i0 + m) * DD + d] = f2bf(a);   // feat is bf16 downstream anyway
  }
}

// MFMA MLP [verified, unchanged]: hidden = feat @ W1 (bf16 in, f32 acc), then
// sum(relu(hidden)*w2). 256 blocks x 512 threads (8 waves). Block stages
// feat[BM=32][256] bf16 in LDS (rows padded to 264 -> 2-way banks on b128
// reads). Wave w owns N-slice [32w,32w+32): 2Mx2N tiles x 8 K-steps of
// mfma_f32_16x16x32_bf16; B-frags straight from L2-resident W1bfT.
__global__ __launch_bounds__(512, 2) void k_mlp(const int* __restrict__ types,
                                                const float* __restrict__ emb,
                                                const unsigned short* __restrict__ aggbf,
                                                const unsigned short* __restrict__ W1bfT,
                                                const float* __restrict__ w2,
                                                float* __restrict__ out) {
  __shared__ unsigned short sA[BM][264];  // 16.5 KB
  __shared__ float sred[8];
  const int tid = threadIdx.x;
  const int n0 = blockIdx.x * BM;

  // stage feat = concat(emb[type], aggbf) as bf16: 32 rows x 64 chunks of 4
  for (int idx = tid; idx < BM * 64; idx += 512) {
    int row = idx >> 6;
    int cb = idx & 63;          // 4-col chunk
    int node = n0 + row;
    ushort4 u;
    if (cb < 32) {
      float4 v = *(const float4*)&emb[types[node] * DD + 4 * cb];
      u.x = f2bf(v.x); u.y = f2bf(v.y); u.z = f2bf(v.z); u.w = f2bf(v.w);
    } else {
      u = *(const ushort4*)&aggbf[(size_t)node * DD + 4 * (cb - 32)];
    }
    *(ushort4*)&sA[row][4 * cb] = u;
  }
  __syncthreads();

  const int lane = tid & 63;
  const int wv = tid >> 6;      // 0..7 -> N-slice
  const int nb = wv * 32;
  const int l15 = lane & 15;
  const int g = lane >> 4;      // 0..3 -> k-subgroup
  f32x4 acc00 = {}, acc01 = {}, acc10 = {}, acc11 = {};

  const unsigned short* bp0 = W1bfT + (nb + l15) * HH + 8 * g;
  const unsigned short* bp1 = bp0 + 16 * HH;
#pragma unroll
  for (int ks = 0; ks < 8; ++ks) {
    bf16x8 a0 = *(const bf16x8*)&sA[l15][ks * 32 + 8 * g];
    bf16x8 a1 = *(const bf16x8*)&sA[16 + l15][ks * 32 + 8 * g];
    bf16x8 b0 = *(const bf16x8*)(bp0 + ks * 32);
    bf16x8 b1 = *(const bf16x8*)(bp1 + ks * 32);
    acc00 = __builtin_amdgcn_mfma_f32_16x16x32_bf16(a0, b0, acc00, 0, 0, 0);
    acc01 = __builtin_amdgcn_mfma_f32_16x16x32_bf16(a0, b1, acc01, 0, 0, 0);
    acc10 = __builtin_amdgcn_mfma_f32_16x16x32_bf16(a1, b0, acc10, 0, 0, 0);
    acc11 = __builtin_amdgcn_mfma_f32_16x16x32_bf16(a1, b1, acc11, 0, 0, 0);
  }

  const float w2a = w2[nb + l15];
  const float w2b = w2[nb + 16 + l15];
  float p = 0.0f;
#pragma unroll
  for (int i = 0; i < 4; ++i) {
    p += fmaxf(acc00[i], 0.0f) * w2a;
    p += fmaxf(acc10[i], 0.0f) * w2a;
    p += fmaxf(acc01[i], 0.0f) * w2b;
    p += fmaxf(acc11[i], 0.0f) * w2b;
  }
#pragma unroll
  for (int off = 32; off; off >>= 1) p += __shfl_down(p, off);  // wave64 reduce
  if (lane == 0) sred[wv] = p;
  __syncthreads();
  if (tid == 0) {
    float t = 0.0f;
#pragma unroll
    for (int q = 0; q < 8; ++q) t += sred[q];
    atomicAdd(out, t * KJ2KCAL);
  }
}

extern "C" void kernel_launch(void* const* d_in, const int* in_sizes, int n_in,
                              void* d_out, int out_size, void* d_ws, size_t ws_size,
                              hipStream_t stream) {
  const float* pos = (const float*)d_in[0];
  const int*   typ = (const int*)d_in[1];
  const float* emb = (const float*)d_in[2];
  const float* W1  = (const float*)d_in[3];
  const float* w2  = (const float*)d_in[4];
  float* out = (float*)d_out;
  unsigned short* aggbf = (unsigned short*)d_ws;                        // 2 MB
  unsigned short* W1bfT = (unsigned short*)((char*)d_ws + (2u << 20));  // 128 KB

  hipLaunchKernelGGL(k_agg, dim3(NATOMS / TI), dim3(256), 0, stream,
                     pos, typ, W1, emb, W1bfT, aggbf, out);
  hipLaunchKernelGGL(k_mlp, dim3(NATOMS / BM), dim3(512), 0, stream,
                     typ, emb, aggbf, W1bfT, w2, out);
}

// Round 13
// 99.591 us; speedup vs baseline: 1.1375x; 1.1375x over previous
//
#include <hip/hip_runtime.h>

#define NATOMS 8192
#define DD 128     // embedding dim
#define HH 256     // hidden dim
#define TI 4       // atoms per block in aggregation -- FROZEN (TI=8 fails: R7/R11)
#define MAXE 128   // max edges per atom (mean ~20, Poisson; 128 is >>6 sigma)
#define BM 32      // nodes per block in MFMA MLP
#define KJ2KCAL 0.2390057361376673f

typedef __attribute__((ext_vector_type(8))) short bf16x8;  // 4 VGPRs
typedef __attribute__((ext_vector_type(4))) float f32x4;
typedef __attribute__((ext_vector_type(2))) float f32x2;   // -> v_pk_*_f32

// fp32 -> bf16 round-to-nearest-even (finite inputs)
__device__ inline unsigned short f2bf(float x) {
  unsigned int b = __builtin_bit_cast(unsigned int, x);
  b += 0x7FFFu + ((b >> 16) & 1u);
  return (unsigned short)(b >> 16);
}

// k_agg [R10-passing structure; staging reverted (R12 regression); only change
// vs R10: the sweep processes TWO j's per lane-iteration (j and j+4096) with
// packed-f32 pairs so the core math issues as v_pk_{add,mul,fma}_f32 (2x fp32
// per instr, IEEE per component -> BIT-IDENTICAL values; same expression
// chain, same mask, same ballot bit<->j mapping, chunks c and c+64 each
// written once). R12 counters: k_agg is VALU-issue-bound (55% busy, 0.8% HBM)
// -> packing attacks the measured bottleneck.]
//  - blocks 0..63 also transpose W1 -> bf16 W1bfT; block 0 zeroes out.
//  - ballot sweep [verified R9/R10]; expand recomputes d2/w with textually
//    identical expressions; order j-ascending. TI=4 frozen.
__global__ __launch_bounds__(256) void k_agg(const float* __restrict__ pos,
                                             const int* __restrict__ types,
                                             const float* __restrict__ W1,
                                             const float* __restrict__ emb,
                                             unsigned short* __restrict__ W1bfT,
                                             unsigned short* __restrict__ aggbf,
                                             float* __restrict__ out) {
  __shared__ unsigned long long smask[TI][NATOMS / 64];  // 4 KB
  __shared__ float sw[TI][MAXE];
  __shared__ int   srow[TI][MAXE];
  __shared__ int   scnt[TI];
  const int tid = threadIdx.x;
  const int i0 = blockIdx.x * TI;

  // merged one-time prep (identical values to verified k_prep)
  if (blockIdx.x < 64) {
    int t = blockIdx.x * 256 + tid;         // 0..16383
    if (t == 0) out[0] = 0.0f;
    int n = t & 255;
    int kb = (t >> 8) * 4;                  // 0,4,..,252
#pragma unroll
    for (int i = 0; i < 4; ++i)
      W1bfT[n * HH + kb + i] = f2bf(W1[(kb + i) * HH + n]);  // read coalesced in n
  }

  float pix[TI], piy[TI], piz[TI];
#pragma unroll
  for (int m = 0; m < TI; ++m) {   // uniform addresses -> scalar loads
    pix[m] = 10.0f * pos[(i0 + m) * 3 + 0];
    piy[m] = 10.0f * pos[(i0 + m) * 3 + 1];
    piz[m] = 10.0f * pos[(i0 + m) * 3 + 2];
  }

  // sweep, 2 j's per lane-iter: j (chunks 0..63) and j+4096 (chunks 64..127).
  // Per-j math is the exact verified chain; .x/.y are independent lanes of
  // packed ops. Ballot bit r <-> j = 64c + r, unchanged.
#pragma unroll 4
  for (int j = tid; j < NATOMS / 2; j += 256) {
    const int j1 = j + NATOMS / 2;
    f32x2 rx = {pos[j * 3 + 0], pos[j1 * 3 + 0]};
    f32x2 ry = {pos[j * 3 + 1], pos[j1 * 3 + 1]};
    f32x2 rz = {pos[j * 3 + 2], pos[j1 * 3 + 2]};
    f32x2 pjx = 10.0f * rx;        // pk_mul; 10*x exact same op as verified
    f32x2 pjy = 10.0f * ry;
    f32x2 pjz = 10.0f * rz;
    int c0 = j >> 6;               // wave-uniform chunk ids
    int c1 = j1 >> 6;
#pragma unroll
    for (int m = 0; m < TI; ++m) {
      f32x2 dx = pix[m] - pjx;     // pk_add (splat - vec)
      f32x2 dy = piy[m] - pjy;
      f32x2 dz = piz[m] - pjz;
      f32x2 d2 = dx * dx;          // pk_mul
      d2.x = fmaf(dy.x, dy.x, d2.x);   // pairs SLP-merge to pk_fma
      d2.y = fmaf(dy.y, dy.y, d2.y);
      d2.x = fmaf(dz.x, dz.x, d2.x);
      d2.y = fmaf(dz.y, dz.y, d2.y);
      // ref mask: d2 > 1e-12 && sqrt(d2) <= 5  <=>  1e-12 < d2 <= 25
      unsigned long long b0 = __ballot(d2.x > 1e-12f && d2.x <= 25.0f);
      unsigned long long b1 = __ballot(d2.y > 1e-12f && d2.y <= 25.0f);
      if ((tid & 63) == 0) {
        smask[m][c0] = b0;
        smask[m][c1] = b1;
      }
    }
  }
  __syncthreads();

  // scan + expand [verbatim R10]: wave m handles atom m; lane l owns chunks
  // {2l, 2l+1}; recompute d2/w with textually identical expressions.
  {
    const int m = tid >> 6;        // 0..3 (4 waves)
    const int l = tid & 63;
    unsigned long long mA = smask[m][2 * l];
    unsigned long long mB = smask[m][2 * l + 1];
    int cA = __popcll(mA), cB = __popcll(mB);
    int s = cA + cB;
    int scan = s;                  // inclusive prefix over 64 lanes
#pragma unroll
    for (int off = 1; off < 64; off <<= 1) {
      int t = __shfl_up(scan, off);
      if (l >= off) scan += t;
    }
    int excl = scan - s;
    if (l == 63) scnt[m] = scan;   // per-atom total
    float px = 10.0f * pos[(i0 + m) * 3 + 0];
    float py = 10.0f * pos[(i0 + m) * 3 + 1];
    float pz = 10.0f * pos[(i0 + m) * 3 + 2];
#pragma unroll
    for (int h = 0; h < 2; ++h) {
      unsigned long long mask = h ? mB : mA;
      int base = h ? excl + cA : excl;
      int cbase = 64 * (2 * l + h);
      while (mask) {
        int r = __ffsll((long long)mask) - 1;
        mask &= mask - 1;
        int j = cbase + r;
        if (base < MAXE) {
          float pjx = 10.0f * pos[j * 3 + 0];
          float pjy = 10.0f * pos[j * 3 + 1];
          float pjz = 10.0f * pos[j * 3 + 2];
          float dx = px - pjx, dy = py - pjy, dz = pz - pjz;
          float d2 = dx * dx;
          d2 = fmaf(dy, dy, d2);
          d2 = fmaf(dz, dz, d2);
          float w = __expf(-sqrtf(d2));
          sw[m][base] = w;
          srow[m][base] = types[j] * DD;
        }
        ++base;
      }
    }
  }
  __syncthreads();

  // phase 2 [verbatim R10]: 2 groups of 128 dims; group g -> atoms {g, g+2}
  const int d = tid & (DD - 1);
  const int g = tid >> 7;
#pragma unroll
  for (int mm = 0; mm < TI; mm += 2) {
    int m = g + mm;
    int nc = min(scnt[m], MAXE);
    float a = 0.0f;
#pragma unroll 4
    for (int e = 0; e < nc; ++e)
      a = fmaf(sw[m][e], emb[srow[m][e] + d], a);
    aggbf[(size_t)(i0 + m) * DD + d] = f2bf(a);   // feat is bf16 downstream anyway
  }
}

// MFMA MLP [verified, unchanged]: hidden = feat @ W1 (bf16 in, f32 acc), then
// sum(relu(hidden)*w2). 256 blocks x 512 threads (8 waves). Block stages
// feat[BM=32][256] bf16 in LDS (rows padded to 264 -> 2-way banks on b128
// reads). Wave w owns N-slice [32w,32w+32): 2Mx2N tiles x 8 K-steps of
// mfma_f32_16x16x32_bf16; B-frags straight from L2-resident W1bfT.
__global__ __launch_bounds__(512, 2) void k_mlp(const int* __restrict__ types,
                                                const float* __restrict__ emb,
                                                const unsigned short* __restrict__ aggbf,
                                                const unsigned short* __restrict__ W1bfT,
                                                const float* __restrict__ w2,
                                                float* __restrict__ out) {
  __shared__ unsigned short sA[BM][264];  // 16.5 KB
  __shared__ float sred[8];
  const int tid = threadIdx.x;
  const int n0 = blockIdx.x * BM;

  // stage feat = concat(emb[type], aggbf) as bf16: 32 rows x 64 chunks of 4
  for (int idx = tid; idx < BM * 64; idx += 512) {
    int row = idx >> 6;
    int cb = idx & 63;          // 4-col chunk
    int node = n0 + row;
    ushort4 u;
    if (cb < 32) {
      float4 v = *(const float4*)&emb[types[node] * DD + 4 * cb];
      u.x = f2bf(v.x); u.y = f2bf(v.y); u.z = f2bf(v.z); u.w = f2bf(v.w);
    } else {
      u = *(const ushort4*)&aggbf[(size_t)node * DD + 4 * (cb - 32)];
    }
    *(ushort4*)&sA[row][4 * cb] = u;
  }
  __syncthreads();

  const int lane = tid & 63;
  const int wv = tid >> 6;      // 0..7 -> N-slice
  const int nb = wv * 32;
  const int l15 = lane & 15;
  const int g = lane >> 4;      // 0..3 -> k-subgroup
  f32x4 acc00 = {}, acc01 = {}, acc10 = {}, acc11 = {};

  const unsigned short* bp0 = W1bfT + (nb + l15) * HH + 8 * g;
  const unsigned short* bp1 = bp0 + 16 * HH;
#pragma unroll
  for (int ks = 0; ks < 8; ++ks) {
    bf16x8 a0 = *(const bf16x8*)&sA[l15][ks * 32 + 8 * g];
    bf16x8 a1 = *(const bf16x8*)&sA[16 + l15][ks * 32 + 8 * g];
    bf16x8 b0 = *(const bf16x8*)(bp0 + ks * 32);
    bf16x8 b1 = *(const bf16x8*)(bp1 + ks * 32);
    acc00 = __builtin_amdgcn_mfma_f32_16x16x32_bf16(a0, b0, acc00, 0, 0, 0);
    acc01 = __builtin_amdgcn_mfma_f32_16x16x32_bf16(a0, b1, acc01, 0, 0, 0);
    acc10 = __builtin_amdgcn_mfma_f32_16x16x32_bf16(a1, b0, acc10, 0, 0, 0);
    acc11 = __builtin_amdgcn_mfma_f32_16x16x32_bf16(a1, b1, acc11, 0, 0, 0);
  }

  const float w2a = w2[nb + l15];
  const float w2b = w2[nb + 16 + l15];
  float p = 0.0f;
#pragma unroll
  for (int i = 0; i < 4; ++i) {
    p += fmaxf(acc00[i], 0.0f) * w2a;
    p += fmaxf(acc10[i], 0.0f) * w2a;
    p += fmaxf(acc01[i], 0.0f) * w2b;
    p += fmaxf(acc11[i], 0.0f) * w2b;
  }
#pragma unroll
  for (int off = 32; off; off >>= 1) p += __shfl_down(p, off);  // wave64 reduce
  if (lane == 0) sred[wv] = p;
  __syncthreads();
  if (tid == 0) {
    float t = 0.0f;
#pragma unroll
    for (int q = 0; q < 8; ++q) t += sred[q];
    atomicAdd(out, t * KJ2KCAL);
  }
}

extern "C" void kernel_launch(void* const* d_in, const int* in_sizes, int n_in,
                              void* d_out, int out_size, void* d_ws, size_t ws_size,
                              hipStream_t stream) {
  const float* pos = (const float*)d_in[0];
  const int*   typ = (const int*)d_in[1];
  const float* emb = (const float*)d_in[2];
  const float* W1  = (const float*)d_in[3];
  const float* w2  = (const float*)d_in[4];
  float* out = (float*)d_out;
  unsigned short* aggbf = (unsigned short*)d_ws;                        // 2 MB
  unsigned short* W1bfT = (unsigned short*)((char*)d_ws + (2u << 20));  // 128 KB

  hipLaunchKernelGGL(k_agg, dim3(NATOMS / TI), dim3(256), 0, stream,
                     pos, typ, W1, emb, W1bfT, aggbf, out);
  hipLaunchKernelGGL(k_mlp, dim3(NATOMS / BM), dim3(512), 0, stream,
                     typ, emb, aggbf, W1bfT, w2, out);
}

// Round 14
// 96.428 us; speedup vs baseline: 1.1748x; 1.0328x over previous
//
#include <hip/hip_runtime.h>

#define NATOMS 8192
#define DD 128     // embedding dim
#define HH 256     // hidden dim
#define TI 4       // atoms per block in aggregation -- FROZEN (TI=8 fails: R7/R11)
#define MAXE 128   // max edges per atom (mean ~20, Poisson; 128 is >>6 sigma)
#define BM 32      // nodes per block in MFMA MLP
#define KJ2KCAL 0.2390057361376673f

typedef __attribute__((ext_vector_type(8))) short bf16x8;  // 4 VGPRs
typedef __attribute__((ext_vector_type(4))) float f32x4;

// fp32 -> bf16 round-to-nearest-even (finite inputs)
__device__ inline unsigned short f2bf(float x) {
  unsigned int b = __builtin_bit_cast(unsigned int, x);
  b += 0x7FFFu + ((b >> 16) & 1u);
  return (unsigned short)(b >> 16);
}

// k_agg [verbatim R10 98.2us-verified source: merged prep + ballot sweep +
// unroll4; pk-packing reverted (R13 null)]. TI=4 frozen.
__global__ __launch_bounds__(256) void k_agg(const float* __restrict__ pos,
                                             const int* __restrict__ types,
                                             const float* __restrict__ W1,
                                             const float* __restrict__ emb,
                                             unsigned short* __restrict__ W1bfT,
                                             unsigned short* __restrict__ aggbf,
                                             float* __restrict__ out) {
  __shared__ unsigned long long smask[TI][NATOMS / 64];  // 4 KB
  __shared__ float sw[TI][MAXE];
  __shared__ int   srow[TI][MAXE];
  __shared__ int   scnt[TI];
  const int tid = threadIdx.x;
  const int i0 = blockIdx.x * TI;

  // merged one-time prep (identical values to verified k_prep)
  if (blockIdx.x < 64) {
    int t = blockIdx.x * 256 + tid;         // 0..16383
    if (t == 0) out[0] = 0.0f;
    int n = t & 255;
    int kb = (t >> 8) * 4;                  // 0,4,..,252
#pragma unroll
    for (int i = 0; i < 4; ++i)
      W1bfT[n * HH + kb + i] = f2bf(W1[(kb + i) * HH + n]);  // read coalesced in n
  }

  float pix[TI], piy[TI], piz[TI];
#pragma unroll
  for (int m = 0; m < TI; ++m) {   // uniform addresses -> scalar loads
    pix[m] = 10.0f * pos[(i0 + m) * 3 + 0];
    piy[m] = 10.0f * pos[(i0 + m) * 3 + 1];
    piz[m] = 10.0f * pos[(i0 + m) * 3 + 2];
  }

  // sweep: lanes of a wave cover 64 consecutive j -> ballot bit r <-> j=64c+r
#pragma unroll 4
  for (int j = tid; j < NATOMS; j += 256) {
    float pjx = 10.0f * pos[j * 3 + 0];
    float pjy = 10.0f * pos[j * 3 + 1];
    float pjz = 10.0f * pos[j * 3 + 2];
    int c = j >> 6;                // wave-uniform chunk id
#pragma unroll
    for (int m = 0; m < TI; ++m) {
      float dx = pix[m] - pjx, dy = piy[m] - pjy, dz = piz[m] - pjz;
      float d2 = dx * dx;
      d2 = fmaf(dy, dy, d2);
      d2 = fmaf(dz, dz, d2);
      // ref mask: d2 > 1e-12 && sqrt(d2) <= 5  <=>  1e-12 < d2 <= 25 (fp32-exact)
      unsigned long long bal = __ballot(d2 > 1e-12f && d2 <= 25.0f);
      if ((tid & 63) == 0) smask[m][c] = bal;
    }
  }
  __syncthreads();

  // scan + expand: wave m handles atom m. Lane l owns chunks {2l, 2l+1}.
  {
    const int m = tid >> 6;        // 0..3 (4 waves)
    const int l = tid & 63;
    unsigned long long mA = smask[m][2 * l];
    unsigned long long mB = smask[m][2 * l + 1];
    int cA = __popcll(mA), cB = __popcll(mB);
    int s = cA + cB;
    int scan = s;                  // inclusive prefix over 64 lanes
#pragma unroll
    for (int off = 1; off < 64; off <<= 1) {
      int t = __shfl_up(scan, off);
      if (l >= off) scan += t;
    }
    int excl = scan - s;
    if (l == 63) scnt[m] = scan;   // per-atom total
    float px = 10.0f * pos[(i0 + m) * 3 + 0];
    float py = 10.0f * pos[(i0 + m) * 3 + 1];
    float pz = 10.0f * pos[(i0 + m) * 3 + 2];
#pragma unroll
    for (int h = 0; h < 2; ++h) {
      unsigned long long mask = h ? mB : mA;
      int base = h ? excl + cA : excl;
      int cbase = 64 * (2 * l + h);
      while (mask) {
        int r = __ffsll((long long)mask) - 1;
        mask &= mask - 1;
        int j = cbase + r;
        if (base < MAXE) {
          float pjx = 10.0f * pos[j * 3 + 0];
          float pjy = 10.0f * pos[j * 3 + 1];
          float pjz = 10.0f * pos[j * 3 + 2];
          float dx = px - pjx, dy = py - pjy, dz = pz - pjz;
          float d2 = dx * dx;
          d2 = fmaf(dy, dy, d2);
          d2 = fmaf(dz, dz, d2);
          float w = __expf(-sqrtf(d2));
          sw[m][base] = w;
          srow[m][base] = types[j] * DD;
        }
        ++base;
      }
    }
  }
  __syncthreads();

  // phase 2 [verbatim R10]: 2 groups of 128 dims; group g -> atoms {g, g+2}
  const int d = tid & (DD - 1);
  const int g = tid >> 7;
#pragma unroll
  for (int mm = 0; mm < TI; mm += 2) {
    int m = g + mm;
    int nc = min(scnt[m], MAXE);
    float a = 0.0f;
#pragma unroll 4
    for (int e = 0; e < nc; ++e)
      a = fmaf(sw[m][e], emb[srow[m][e] + d], a);
    aggbf[(size_t)(i0 + m) * DD + d] = f2bf(a);   // feat is bf16 downstream anyway
  }
}

// MFMA MLP [R10-verified except the LAST STEP]: hidden = feat @ W1 (bf16 in,
// f32 acc), then sum(relu(hidden)*w2). The 256-block single-address
// atomicAdd(out) tail is replaced by a per-block partial store (part[bid]);
// same per-block value, same scaling expression. Theory: 256 serialized
// same-address L2 atomics were the ~20us invisible tail (explains R0-R3's
// k_mlp invariance at VALUBusy 17%).
__global__ __launch_bounds__(512, 2) void k_mlp(const int* __restrict__ types,
                                                const float* __restrict__ emb,
                                                const unsigned short* __restrict__ aggbf,
                                                const unsigned short* __restrict__ W1bfT,
                                                const float* __restrict__ w2,
                                                float* __restrict__ part) {
  __shared__ unsigned short sA[BM][264];  // 16.5 KB
  __shared__ float sred[8];
  const int tid = threadIdx.x;
  const int n0 = blockIdx.x * BM;

  // stage feat = concat(emb[type], aggbf) as bf16: 32 rows x 64 chunks of 4
  for (int idx = tid; idx < BM * 64; idx += 512) {
    int row = idx >> 6;
    int cb = idx & 63;          // 4-col chunk
    int node = n0 + row;
    ushort4 u;
    if (cb < 32) {
      float4 v = *(const float4*)&emb[types[node] * DD + 4 * cb];
      u.x = f2bf(v.x); u.y = f2bf(v.y); u.z = f2bf(v.z); u.w = f2bf(v.w);
    } else {
      u = *(const ushort4*)&aggbf[(size_t)node * DD + 4 * (cb - 32)];
    }
    *(ushort4*)&sA[row][4 * cb] = u;
  }
  __syncthreads();

  const int lane = tid & 63;
  const int wv = tid >> 6;      // 0..7 -> N-slice
  const int nb = wv * 32;
  const int l15 = lane & 15;
  const int g = lane >> 4;      // 0..3 -> k-subgroup
  f32x4 acc00 = {}, acc01 = {}, acc10 = {}, acc11 = {};

  const unsigned short* bp0 = W1bfT + (nb + l15) * HH + 8 * g;
  const unsigned short* bp1 = bp0 + 16 * HH;
#pragma unroll
  for (int ks = 0; ks < 8; ++ks) {
    bf16x8 a0 = *(const bf16x8*)&sA[l15][ks * 32 + 8 * g];
    bf16x8 a1 = *(const bf16x8*)&sA[16 + l15][ks * 32 + 8 * g];
    bf16x8 b0 = *(const bf16x8*)(bp0 + ks * 32);
    bf16x8 b1 = *(const bf16x8*)(bp1 + ks * 32);
    acc00 = __builtin_amdgcn_mfma_f32_16x16x32_bf16(a0, b0, acc00, 0, 0, 0);
    acc01 = __builtin_amdgcn_mfma_f32_16x16x32_bf16(a0, b1, acc01, 0, 0, 0);
    acc10 = __builtin_amdgcn_mfma_f32_16x16x32_bf16(a1, b0, acc10, 0, 0, 0);
    acc11 = __builtin_amdgcn_mfma_f32_16x16x32_bf16(a1, b1, acc11, 0, 0, 0);
  }

  const float w2a = w2[nb + l15];
  const float w2b = w2[nb + 16 + l15];
  float p = 0.0f;
#pragma unroll
  for (int i = 0; i < 4; ++i) {
    p += fmaxf(acc00[i], 0.0f) * w2a;
    p += fmaxf(acc10[i], 0.0f) * w2a;
    p += fmaxf(acc01[i], 0.0f) * w2b;
    p += fmaxf(acc11[i], 0.0f) * w2b;
  }
#pragma unroll
  for (int off = 32; off; off >>= 1) p += __shfl_down(p, off);  // wave64 reduce
  if (lane == 0) sred[wv] = p;
  __syncthreads();
  if (tid == 0) {
    float t = 0.0f;
#pragma unroll
    for (int q = 0; q < 8; ++q) t += sred[q];
    part[blockIdx.x] = t * KJ2KCAL;   // plain store, no contention
  }
}

// Final reduce: 1 block, 64 threads, sums the 256 per-block partials and
// writes the output scalar directly (overwrites the poison).
__global__ void k_fin(const float* __restrict__ part, float* __restrict__ out) {
  int l = threadIdx.x;   // 0..63
  float s = part[l] + part[l + 64] + part[l + 128] + part[l + 192];
#pragma unroll
  for (int off = 32; off; off >>= 1) s += __shfl_down(s, off);
  if (l == 0) out[0] = s;
}

extern "C" void kernel_launch(void* const* d_in, const int* in_sizes, int n_in,
                              void* d_out, int out_size, void* d_ws, size_t ws_size,
                              hipStream_t stream) {
  const float* pos = (const float*)d_in[0];
  const int*   typ = (const int*)d_in[1];
  const float* emb = (const float*)d_in[2];
  const float* W1  = (const float*)d_in[3];
  const float* w2  = (const float*)d_in[4];
  float* out = (float*)d_out;
  unsigned short* aggbf = (unsigned short*)d_ws;                        // 2 MB
  unsigned short* W1bfT = (unsigned short*)((char*)d_ws + (2u << 20));  // 128 KB
  float*          part  = (float*)((char*)d_ws + (4u << 20));           // 1 KB

  hipLaunchKernelGGL(k_agg, dim3(NATOMS / TI), dim3(256), 0, stream,
                     pos, typ, W1, emb, W1bfT, aggbf, out);
  hipLaunchKernelGGL(k_mlp, dim3(NATOMS / BM), dim3(512), 0, stream,
                     typ, emb, aggbf, W1bfT, w2, part);
  hipLaunchKernelGGL(k_fin, dim3(1), dim3(64), 0, stream, part, out);
}